// Round 1
// baseline (346.917 us; speedup 1.0000x reference)
//
#include <hip/hip_runtime.h>

// ---- static config (matches reference) ----
constexpr int kNImgs   = 9;
constexpr int kC       = 24;
constexpr int kHF      = 112, kWF = 112;
constexpr int kHD      = 56,  kWD = 56;
constexpr int kNPix    = kHD * kWD;              // 3136
constexpr int kNPlanes = 64;
constexpr int kPtsPerRef = kNPlanes * kNPix;     // 200704 = 784 * 256
constexpr int kEdgesPerRef = 8;
constexpr int kNEdges  = kNImgs * kEdgesPerRef;  // 72
constexpr int kFeatPix = kHF * kWF;              // 12544
constexpr int kFeatPerImg = kC * kFeatPix;       // 301056

// ---------- small 3x3 helpers ----------
__device__ inline void mm3(const float* A, const float* B, float* C) {
#pragma unroll
  for (int i = 0; i < 3; ++i)
#pragma unroll
    for (int j = 0; j < 3; ++j)
      C[i*3+j] = A[i*3+0]*B[0*3+j] + A[i*3+1]*B[1*3+j] + A[i*3+2]*B[2*3+j];
}

__device__ inline void inv3(const float* A, float* I) {
  float a=A[0],b=A[1],c=A[2],d=A[3],e=A[4],f=A[5],g=A[6],h=A[7],i=A[8];
  float c00 = e*i - f*h;
  float c01 = -(d*i - f*g);
  float c02 = d*h - e*g;
  float det = a*c00 + b*c01 + c*c02;
  float r = 1.0f / det;
  I[0] = c00*r;           I[1] = (c*h - b*i)*r;  I[2] = (b*f - c*e)*r;
  I[3] = c01*r;           I[4] = (a*i - c*g)*r;  I[5] = (c*d - a*f)*r;
  I[6] = c02*r;           I[7] = (b*g - a*h)*r;  I[8] = (a*e - b*d)*r;
}

// ---------- transpose feats [N,C,HF,WF] -> [N,HF,WF,C] ----------
__global__ __launch_bounds__(256)
void transpose_feats_kernel(const float* __restrict__ f, float* __restrict__ ft) {
  int idx = blockIdx.x * 256 + threadIdx.x;
  if (idx >= kNImgs * kFeatPerImg) return;
  int n  = idx / kFeatPerImg;
  int r  = idx - n * kFeatPerImg;
  int c  = r / kFeatPix;
  int yx = r - c * kFeatPix;
  ft[((size_t)n * kFeatPix + yx) * kC + c] = f[idx];
}

// ---------- main fused kernel ----------
// thread = one (ref n, plane d, pixel p) point; writes 24 channel variances.
template <bool TR>
__global__ __launch_bounds__(256)
void psv_var_kernel(const float* __restrict__ feats,   // [N,C,HF,WF] (used if !TR)
                    const float* __restrict__ featsT,  // [N,HF,WF,C] (used if TR)
                    const float* __restrict__ rotmats, // [N,3,3]
                    const float* __restrict__ tvecs,   // [N,3]
                    const float* __restrict__ Kmat,    // [N,3,3]
                    const int*   __restrict__ edges,   // [2,72]
                    float* __restrict__ out) {         // [N,C,D,HD,WD]
  __shared__ float sM[kEdgesPerRef][9];
  __shared__ float sB[kEdgesPerRef][3];
  __shared__ int   sSrc[kEdgesPerRef];

  const int tid = blockIdx.x * 256 + threadIdx.x;
  const int n = tid / kPtsPerRef;  // block never straddles refs (200704 % 256 == 0)

  if (threadIdx.x < kEdgesPerRef) {
    const int e  = n * kEdgesPerRef + threadIdx.x;
    const int re = edges[e];            // ref row
    const int se = edges[kNEdges + e];  // src row
    sSrc[threadIdx.x] = se;

    const float* Rr = rotmats + re * 9;
    const float* Rs = rotmats + se * 9;
    const float* Kr = Kmat + re * 9;
    const float* Ks = Kmat + se * 9;
    const float* tr = tvecs + re * 3;
    const float* ts = tvecs + se * 3;

    float RrT[9];
#pragma unroll
    for (int i = 0; i < 3; ++i)
#pragma unroll
      for (int j = 0; j < 3; ++j) RrT[i*3+j] = Rr[j*3+i];

    float Kinv[9], A[9], T1[9], M[9];
    inv3(Kr, Kinv);
    mm3(Rs, RrT, A);       // A = R_src * R_ref^T
    mm3(A, Kinv, T1);
    mm3(Ks, T1, M);        // M = K_src * A * K_ref^-1

    float At0 = A[0]*tr[0] + A[1]*tr[1] + A[2]*tr[2];
    float At1 = A[3]*tr[0] + A[4]*tr[1] + A[5]*tr[2];
    float At2 = A[6]*tr[0] + A[7]*tr[1] + A[8]*tr[2];
    float bv0 = ts[0] - At0, bv1 = ts[1] - At1, bv2 = ts[2] - At2;
#pragma unroll
    for (int i = 0; i < 9; ++i) sM[threadIdx.x][i] = M[i];
#pragma unroll
    for (int i = 0; i < 3; ++i)
      sB[threadIdx.x][i] = Ks[i*3+0]*bv0 + Ks[i*3+1]*bv1 + Ks[i*3+2]*bv2;
  }
  __syncthreads();

  const int local = tid - n * kPtsPerRef;
  const int d = local / kNPix;
  const int p = local - d * kNPix;
  const int h = p / kWD;
  const int w = p - h * kWD;

  const float u = (float)w * (447.0f / 55.0f);   // linspace(0,447,56)
  const float v = (float)h * (447.0f / 55.0f);
  const float depth = 0.5f + 0.05f * (float)d;

  float acc[kC], accsq[kC];
#pragma unroll
  for (int c = 0; c < kC; ++c) { acc[c] = 0.0f; accsq[c] = 0.0f; }

  for (int j = 0; j < kEdgesPerRef; ++j) {
    const float* M = sM[j];
    const float px = depth * (M[0]*u + M[1]*v + M[2]) + sB[j][0];
    const float py = depth * (M[3]*u + M[4]*v + M[5]) + sB[j][1];
    const float pz = depth * (M[6]*u + M[7]*v + M[8]) + sB[j][2];
    const float z  = fabsf(pz) + 1e-8f;

    // gx = px/z/447*2-1 ; x = (gx+1)*0.5*111  (align_corners=True)
    const float gx = (px / z) * (2.0f / 447.0f) - 1.0f;
    const float gy = (py / z) * (2.0f / 447.0f) - 1.0f;
    const float x  = (gx + 1.0f) * (0.5f * 111.0f);
    const float y  = (gy + 1.0f) * (0.5f * 111.0f);

    const float x0 = floorf(x), y0 = floorf(y);
    const float wx = x - x0, wy = y - y0;
    const bool vx0 = (x0 >= 0.0f)  && (x0 <= 111.0f);
    const bool vx1 = (x0 >= -1.0f) && (x0 <= 110.0f);
    const bool vy0 = (y0 >= 0.0f)  && (y0 <= 111.0f);
    const bool vy1 = (y0 >= -1.0f) && (y0 <= 110.0f);
    const float w00 = (vx0 && vy0) ? (1.0f - wx) * (1.0f - wy) : 0.0f;
    const float w01 = (vx1 && vy0) ? wx * (1.0f - wy) : 0.0f;
    const float w10 = (vx0 && vy1) ? (1.0f - wx) * wy : 0.0f;
    const float w11 = (vx1 && vy1) ? wx * wy : 0.0f;

    const int xc0 = (int)fminf(fmaxf(x0,        0.0f), 111.0f);
    const int xc1 = (int)fminf(fmaxf(x0 + 1.0f, 0.0f), 111.0f);
    const int yc0 = (int)fminf(fmaxf(y0,        0.0f), 111.0f);
    const int yc1 = (int)fminf(fmaxf(y0 + 1.0f, 0.0f), 111.0f);

    const int src = sSrc[j];
    if constexpr (TR) {
      const float* base = featsT + (size_t)src * kFeatPix * kC;
      const int o00 = (yc0 * kWF + xc0) * kC;
      const int o01 = (yc0 * kWF + xc1) * kC;
      const int o10 = (yc1 * kWF + xc0) * kC;
      const int o11 = (yc1 * kWF + xc1) * kC;
#pragma unroll
      for (int i = 0; i < kC / 4; ++i) {
        const float4 f00 = *(const float4*)(base + o00 + 4*i);
        const float4 f01 = *(const float4*)(base + o01 + 4*i);
        const float4 f10 = *(const float4*)(base + o10 + 4*i);
        const float4 f11 = *(const float4*)(base + o11 + 4*i);
        float v0 = w00*f00.x + w01*f01.x + w10*f10.x + w11*f11.x;
        float v1 = w00*f00.y + w01*f01.y + w10*f10.y + w11*f11.y;
        float v2 = w00*f00.z + w01*f01.z + w10*f10.z + w11*f11.z;
        float v3 = w00*f00.w + w01*f01.w + w10*f10.w + w11*f11.w;
        acc[4*i+0] += v0; accsq[4*i+0] += v0*v0;
        acc[4*i+1] += v1; accsq[4*i+1] += v1*v1;
        acc[4*i+2] += v2; accsq[4*i+2] += v2*v2;
        acc[4*i+3] += v3; accsq[4*i+3] += v3*v3;
      }
    } else {
      const float* base = feats + (size_t)src * kFeatPerImg;
      const int o00 = yc0 * kWF + xc0;
      const int o01 = yc0 * kWF + xc1;
      const int o10 = yc1 * kWF + xc0;
      const int o11 = yc1 * kWF + xc1;
#pragma unroll
      for (int c = 0; c < kC; ++c) {
        const float* bc = base + c * kFeatPix;
        float val = w00*bc[o00] + w01*bc[o01] + w10*bc[o10] + w11*bc[o11];
        acc[c] += val; accsq[c] += val*val;
      }
    }
  }

  // variance epilogue: counts == 8 per ref (ref row is repeat(arange(9),8))
  float* op = out + ((size_t)n * kC * kNPlanes + d) * kNPix + p;
#pragma unroll
  for (int c = 0; c < kC; ++c) {
    float mean = acc[c] * 0.125f;
    float msq  = accsq[c] * 0.125f;
    op[(size_t)c * (kNPlanes * kNPix)] = msq - mean * mean;
  }
}

extern "C" void kernel_launch(void* const* d_in, const int* in_sizes, int n_in,
                              void* d_out, int out_size, void* d_ws, size_t ws_size,
                              hipStream_t stream) {
  const float* feats  = (const float*)d_in[0];
  const float* rot    = (const float*)d_in[1];
  const float* tv     = (const float*)d_in[2];
  const float* Kmat   = (const float*)d_in[3];
  const int*   edges  = (const int*)d_in[4];
  float* out = (float*)d_out;

  const size_t featsTBytes = (size_t)kNImgs * kFeatPix * kC * sizeof(float);
  const int nMain = kNImgs * kPtsPerRef;            // 1,806,336
  const int gridMain = nMain / 256;                 // 7056

  if (ws_size >= featsTBytes) {
    float* featsT = (float*)d_ws;
    const int nT = kNImgs * kFeatPerImg;            // 2,709,504
    transpose_feats_kernel<<<(nT + 255) / 256, 256, 0, stream>>>(feats, featsT);
    psv_var_kernel<true><<<gridMain, 256, 0, stream>>>(feats, featsT, rot, tv, Kmat, edges, out);
  } else {
    psv_var_kernel<false><<<gridMain, 256, 0, stream>>>(feats, nullptr, rot, tv, Kmat, edges, out);
  }
}

// Round 2
// 199.469 us; speedup vs baseline: 1.7392x; 1.7392x over previous
//
#include <hip/hip_runtime.h>

// ---- static config (matches reference) ----
constexpr int kNImgs   = 9;
constexpr int kC       = 24;
constexpr int kHF      = 112, kWF = 112;
constexpr int kHD      = 56,  kWD = 56;
constexpr int kNPix    = kHD * kWD;              // 3136
constexpr int kNPlanes = 64;
constexpr int kPtsPerRef = kNPlanes * kNPix;     // 200704 = 784 * 256
constexpr int kEdgesPerRef = 8;
constexpr int kNEdges  = kNImgs * kEdgesPerRef;  // 72
constexpr int kFeatPix = kHF * kWF;              // 12544
constexpr int kFeatPerImg = kC * kFeatPix;       // 301056

typedef _Float16 half8 __attribute__((ext_vector_type(8)));

// ---------- small 3x3 helpers ----------
__device__ inline void mm3(const float* A, const float* B, float* C) {
#pragma unroll
  for (int i = 0; i < 3; ++i)
#pragma unroll
    for (int j = 0; j < 3; ++j)
      C[i*3+j] = A[i*3+0]*B[0*3+j] + A[i*3+1]*B[1*3+j] + A[i*3+2]*B[2*3+j];
}

__device__ inline void inv3(const float* A, float* I) {
  float a=A[0],b=A[1],c=A[2],d=A[3],e=A[4],f=A[5],g=A[6],h=A[7],i=A[8];
  float c00 = e*i - f*h;
  float c01 = -(d*i - f*g);
  float c02 = d*h - e*g;
  float det = a*c00 + b*c01 + c*c02;
  float r = 1.0f / det;
  I[0] = c00*r;           I[1] = (c*h - b*i)*r;  I[2] = (b*f - c*e)*r;
  I[3] = c01*r;           I[4] = (a*i - c*g)*r;  I[5] = (c*d - a*f)*r;
  I[6] = c02*r;           I[7] = (b*g - a*h)*r;  I[8] = (a*e - b*d)*r;
}

// ---------- transpose+convert feats [N,C,HF,WF] f32 -> [N,HF,WF,C] f16 ----------
__global__ __launch_bounds__(256)
void transpose_feats_kernel(const float* __restrict__ f, _Float16* __restrict__ ft) {
  int idx = blockIdx.x * 256 + threadIdx.x;
  if (idx >= kNImgs * kFeatPerImg) return;
  int n  = idx / kFeatPerImg;
  int r  = idx - n * kFeatPerImg;
  int c  = r / kFeatPix;
  int yx = r - c * kFeatPix;
  ft[((size_t)n * kFeatPix + yx) * kC + c] = (_Float16)f[idx];
}

// ---------- main fused kernel ----------
// thread = one (ref n, plane d, pixel p) point; writes 24 channel variances.
template <bool TR>
__global__ __launch_bounds__(256)
void psv_var_kernel(const float* __restrict__ feats,      // [N,C,HF,WF] f32 (used if !TR)
                    const _Float16* __restrict__ featsT,  // [N,HF,WF,C] f16 (used if TR)
                    const float* __restrict__ rotmats,    // [N,3,3]
                    const float* __restrict__ tvecs,      // [N,3]
                    const float* __restrict__ Kmat,       // [N,3,3]
                    const int*   __restrict__ edges,      // [2,72]
                    float* __restrict__ out) {            // [N,C,D,HD,WD]
  __shared__ float sM[kEdgesPerRef][9];
  __shared__ float sB[kEdgesPerRef][3];
  __shared__ int   sSrc[kEdgesPerRef];

  // XCD-contiguous swizzle: 7056 blocks = 8 * 882 exactly -> bijective.
  const int nwg = gridDim.x;
  int bid = blockIdx.x;
  if ((nwg & 7) == 0) {
    const int cpx = nwg >> 3;
    bid = (bid & 7) * cpx + (bid >> 3);
  }

  const int tid = bid * 256 + threadIdx.x;
  const int n = tid / kPtsPerRef;  // block never straddles refs (200704 % 256 == 0)

  if (threadIdx.x < kEdgesPerRef) {
    const int e  = n * kEdgesPerRef + threadIdx.x;
    const int re = edges[e];            // ref row
    const int se = edges[kNEdges + e];  // src row
    sSrc[threadIdx.x] = se;

    const float* Rr = rotmats + re * 9;
    const float* Rs = rotmats + se * 9;
    const float* Kr = Kmat + re * 9;
    const float* Ks = Kmat + se * 9;
    const float* tr = tvecs + re * 3;
    const float* ts = tvecs + se * 3;

    float RrT[9];
#pragma unroll
    for (int i = 0; i < 3; ++i)
#pragma unroll
      for (int j = 0; j < 3; ++j) RrT[i*3+j] = Rr[j*3+i];

    float Kinv[9], A[9], T1[9], M[9];
    inv3(Kr, Kinv);
    mm3(Rs, RrT, A);       // A = R_src * R_ref^T
    mm3(A, Kinv, T1);
    mm3(Ks, T1, M);        // M = K_src * A * K_ref^-1

    float At0 = A[0]*tr[0] + A[1]*tr[1] + A[2]*tr[2];
    float At1 = A[3]*tr[0] + A[4]*tr[1] + A[5]*tr[2];
    float At2 = A[6]*tr[0] + A[7]*tr[1] + A[8]*tr[2];
    float bv0 = ts[0] - At0, bv1 = ts[1] - At1, bv2 = ts[2] - At2;
#pragma unroll
    for (int i = 0; i < 9; ++i) sM[threadIdx.x][i] = M[i];
#pragma unroll
    for (int i = 0; i < 3; ++i)
      sB[threadIdx.x][i] = Ks[i*3+0]*bv0 + Ks[i*3+1]*bv1 + Ks[i*3+2]*bv2;
  }
  __syncthreads();

  const int local = tid - n * kPtsPerRef;
  const int d = local / kNPix;
  const int p = local - d * kNPix;
  const int h = p / kWD;
  const int w = p - h * kWD;

  const float u = (float)w * (447.0f / 55.0f);   // linspace(0,447,56)
  const float v = (float)h * (447.0f / 55.0f);
  const float depth = 0.5f + 0.05f * (float)d;

  float acc[kC], accsq[kC];
#pragma unroll
  for (int c = 0; c < kC; ++c) { acc[c] = 0.0f; accsq[c] = 0.0f; }

#pragma unroll 2
  for (int j = 0; j < kEdgesPerRef; ++j) {
    const float* M = sM[j];
    const float px = depth * (M[0]*u + M[1]*v + M[2]) + sB[j][0];
    const float py = depth * (M[3]*u + M[4]*v + M[5]) + sB[j][1];
    const float pz = depth * (M[6]*u + M[7]*v + M[8]) + sB[j][2];
    const float rz = 1.0f / (fabsf(pz) + 1e-8f);

    // x = (px/z) * 111/447  (align_corners=True, folded constants)
    const float x = px * rz * (111.0f / 447.0f);
    const float y = py * rz * (111.0f / 447.0f);

    const float x0 = floorf(x), y0 = floorf(y);
    const float wx = x - x0, wy = y - y0;
    const bool vx0 = (x0 >= 0.0f)  && (x0 <= 111.0f);
    const bool vx1 = (x0 >= -1.0f) && (x0 <= 110.0f);
    const bool vy0 = (y0 >= 0.0f)  && (y0 <= 111.0f);
    const bool vy1 = (y0 >= -1.0f) && (y0 <= 110.0f);
    const float w00 = (vx0 && vy0) ? (1.0f - wx) * (1.0f - wy) : 0.0f;
    const float w01 = (vx1 && vy0) ? wx * (1.0f - wy) : 0.0f;
    const float w10 = (vx0 && vy1) ? (1.0f - wx) * wy : 0.0f;
    const float w11 = (vx1 && vy1) ? wx * wy : 0.0f;

    const int xc0 = (int)fminf(fmaxf(x0,        0.0f), 111.0f);
    const int xc1 = (int)fminf(fmaxf(x0 + 1.0f, 0.0f), 111.0f);
    const int yc0 = (int)fminf(fmaxf(y0,        0.0f), 111.0f);
    const int yc1 = (int)fminf(fmaxf(y0 + 1.0f, 0.0f), 111.0f);

    const int src = sSrc[j];
    if constexpr (TR) {
      const _Float16* base = featsT + (size_t)src * kFeatPix * kC;
      const int o00 = (yc0 * kWF + xc0) * kC;
      const int o01 = (yc0 * kWF + xc1) * kC;
      const int o10 = (yc1 * kWF + xc0) * kC;
      const int o11 = (yc1 * kWF + xc1) * kC;
#pragma unroll
      for (int i = 0; i < kC / 8; ++i) {          // 3 chunks of 8 f16 channels
        const half8 f00 = *(const half8*)(base + o00 + 8*i);
        const half8 f01 = *(const half8*)(base + o01 + 8*i);
        const half8 f10 = *(const half8*)(base + o10 + 8*i);
        const half8 f11 = *(const half8*)(base + o11 + 8*i);
#pragma unroll
        for (int k = 0; k < 8; ++k) {
          float val = w00 * (float)f00[k] + w01 * (float)f01[k]
                    + w10 * (float)f10[k] + w11 * (float)f11[k];
          const int c = 8*i + k;
          acc[c] += val; accsq[c] += val * val;
        }
      }
    } else {
      const float* base = feats + (size_t)src * kFeatPerImg;
      const int o00 = yc0 * kWF + xc0;
      const int o01 = yc0 * kWF + xc1;
      const int o10 = yc1 * kWF + xc0;
      const int o11 = yc1 * kWF + xc1;
#pragma unroll
      for (int c = 0; c < kC; ++c) {
        const float* bc = base + c * kFeatPix;
        float val = w00*bc[o00] + w01*bc[o01] + w10*bc[o10] + w11*bc[o11];
        acc[c] += val; accsq[c] += val*val;
      }
    }
  }

  // variance epilogue: counts == 8 per ref (ref row is repeat(arange(9),8))
  float* op = out + ((size_t)n * kC * kNPlanes + d) * kNPix + p;
#pragma unroll
  for (int c = 0; c < kC; ++c) {
    float mean = acc[c] * 0.125f;
    float msq  = accsq[c] * 0.125f;
    op[(size_t)c * (kNPlanes * kNPix)] = msq - mean * mean;
  }
}

extern "C" void kernel_launch(void* const* d_in, const int* in_sizes, int n_in,
                              void* d_out, int out_size, void* d_ws, size_t ws_size,
                              hipStream_t stream) {
  const float* feats  = (const float*)d_in[0];
  const float* rot    = (const float*)d_in[1];
  const float* tv     = (const float*)d_in[2];
  const float* Kmat   = (const float*)d_in[3];
  const int*   edges  = (const int*)d_in[4];
  float* out = (float*)d_out;

  const size_t featsTBytes = (size_t)kNImgs * kFeatPix * kC * sizeof(_Float16);  // 5.4 MB
  const int nMain = kNImgs * kPtsPerRef;            // 1,806,336
  const int gridMain = nMain / 256;                 // 7056 = 8 * 882

  if (ws_size >= featsTBytes) {
    _Float16* featsT = (_Float16*)d_ws;
    const int nT = kNImgs * kFeatPerImg;            // 2,709,504
    transpose_feats_kernel<<<(nT + 255) / 256, 256, 0, stream>>>(feats, featsT);
    psv_var_kernel<true><<<gridMain, 256, 0, stream>>>(feats, featsT, rot, tv, Kmat, edges, out);
  } else {
    psv_var_kernel<false><<<gridMain, 256, 0, stream>>>(feats, nullptr, rot, tv, Kmat, edges, out);
  }
}